// Round 5
// baseline (1113.773 us; speedup 1.0000x reference)
//
#include <hip/hip_runtime.h>

// Problem constants
#define Tn 512
#define Sn 512
#define Bn 8
#define Dn 512
#define Hn 8
#define HDn 64
#define Ln 8
#define Fn 2048
#define SCALE 0.125f

typedef short short8 __attribute__((ext_vector_type(8)));
typedef float floatx4 __attribute__((ext_vector_type(4)));

__device__ __forceinline__ unsigned short f2b(float f) {
    unsigned int u = __float_as_uint(f);
    u += 0x7FFFu + ((u >> 16) & 1u);   // round-to-nearest-even
    return (unsigned short)(u >> 16);
}

// ---------------------------------------------------------------------------
// Prep: (T,B,D) f32 -> (B*T, D) bf16 rows
__global__ __launch_bounds__(256) void to_rows_bf16(const float* __restrict__ in,
                                                    unsigned short* __restrict__ out, int T_) {
    size_t n = (size_t)blockIdx.x * 256 + threadIdx.x;
    size_t total = (size_t)T_ * Bn * Dn;
    if (n >= total) return;
    int d = (int)(n & (Dn - 1));
    size_t rt = n >> 9;              // Dn = 512
    int t = (int)(rt % T_);
    int b = (int)(rt / T_);
    out[n] = f2b(in[((size_t)t * Bn + b) * Dn + d]);
}

// ---------------------------------------------------------------------------
// One-shot weight conversion into a packed bf16 arena + concatenated qkv bias.
// Arena layout (units of 256K = 1<<18 elems): [0..3):qkv  [3]:sao  [4..7):cain
// [7]:cao  [8..12):lin1  [12..16):lin2  [16]:rel(32K)
__global__ __launch_bounds__(256) void conv_all(
    const float* __restrict__ qw, const float* __restrict__ kw, const float* __restrict__ vw,
    const float* __restrict__ sow, const float* __restrict__ ciw, const float* __restrict__ cow,
    const float* __restrict__ l1w, const float* __restrict__ l2w, const float* __restrict__ rel,
    const float* __restrict__ qbias, const float* __restrict__ kbias, const float* __restrict__ vbias,
    unsigned short* __restrict__ wall, float* __restrict__ bqkv) {
    const int Q = 1 << 18;
    const int total = 16 * Q + Ln * HDn * HDn;   // 4227072
    int i = blockIdx.x * 256 + threadIdx.x;
    if (i < total) {
        int seg = i >> 18, r = i & (Q - 1);
        float v;
        if (seg < 3)       v = (seg == 0 ? qw : (seg == 1 ? kw : vw))[r];
        else if (seg == 3) v = sow[r];
        else if (seg < 7)  v = ciw[(size_t)(seg - 4) * Q + r];
        else if (seg == 7) v = cow[r];
        else if (seg < 12) v = l1w[(size_t)(seg - 8) * Q + r];
        else if (seg < 16) v = l2w[(size_t)(seg - 12) * Q + r];
        else               v = rel[r];
        wall[i] = f2b(v);
    }
    int j = i - total;
    if (j >= 0 && j < 3 * Dn)
        bqkv[j] = (j < Dn ? qbias[j] : (j < 2 * Dn ? kbias[j - Dn] : vbias[j - 2 * Dn]));
}

// ---------------------------------------------------------------------------
// Shared epilogue: scatter one 16x16 C tile per (mt,nt) per mode.
// mode 0: f32 row-major   1: bf16 row-major   2: bf16 heads (B,H,T,HD)
// mode 3: bf16 headsT (B,H,HD,T)
// mode 4: fused qkv split: gn<512->Cv heads, <1024->Cv2 heads, else Cv3 headsT
// mode 5: fused kv  split: gn<512->Cv heads, else Cv2 headsT
__device__ __forceinline__ void c_scatter(
    floatx4 v, int gm, int gn, size_t coff, int ldc, float alpha, float bb,
    int mode, int relu, int Tp, void* Cv, void* Cv2, void* Cv3) {
    for (int r = 0; r < 4; ++r) {
        float val = v[r] * alpha + bb;
        if (relu) val = fmaxf(val, 0.0f);
        int m = gm + r;
        if (mode == 0) {
            ((float*)Cv)[coff + (size_t)m * ldc + gn] = val;
        } else if (mode == 1) {
            ((unsigned short*)Cv)[coff + (size_t)m * ldc + gn] = f2b(val);
        } else if (mode == 2) {
            int bq = m / Tp, t = m - bq * Tp;
            ((unsigned short*)Cv)[(((size_t)(bq * Hn + (gn >> 6)) * Tp + t) << 6) + (gn & 63)] = f2b(val);
        } else if (mode == 3) {
            int bq = m / Tp, t = m - bq * Tp;
            ((unsigned short*)Cv)[((size_t)(bq * Hn + (gn >> 6)) * 64 + (gn & 63)) * Tp + t] = f2b(val);
        } else if (mode == 4) {
            int sel = gn >> 9, g2 = gn & 511;
            int bq = m / Tp, t = m - bq * Tp;
            int hh = g2 >> 6, dd = g2 & 63;
            if (sel == 0)
                ((unsigned short*)Cv)[(((size_t)(bq * Hn + hh) * Tp + t) << 6) + dd] = f2b(val);
            else if (sel == 1)
                ((unsigned short*)Cv2)[(((size_t)(bq * Hn + hh) * Tp + t) << 6) + dd] = f2b(val);
            else
                ((unsigned short*)Cv3)[((size_t)(bq * Hn + hh) * 64 + dd) * Tp + t] = f2b(val);
        } else { // mode 5
            int sel = gn >> 9, g2 = gn & 511;
            int bq = m / Tp, t = m - bq * Tp;
            int hh = g2 >> 6, dd = g2 & 63;
            if (sel == 0)
                ((unsigned short*)Cv)[(((size_t)(bq * Hn + hh) * Tp + t) << 6) + dd] = f2b(val);
            else
                ((unsigned short*)Cv2)[((size_t)(bq * Hn + hh) * 64 + dd) * Tp + t] = f2b(val);
        }
    }
}

// ---------------------------------------------------------------------------
// Batched bf16 MFMA GEMM, 64x64 block tile (for small-N / heavily-batched).
__global__ __launch_bounds__(256) void gemm_bf16(
    const unsigned short* __restrict__ A, const unsigned short* __restrict__ W,
    const float* __restrict__ bias, void* __restrict__ Cv, void* __restrict__ Cv2,
    void* __restrict__ Cv3,
    int M, int N, int K, int lda, int ldw, int ldc,
    long sA1, long sA2, long sW1, long sW2, long sC1, long sC2, int zdiv,
    float alpha, int mode, int relu, int Tp) {
    int z = blockIdx.z;
    int z1 = z / zdiv, z2 = z - z1 * zdiv;
    const unsigned short* Ab = A + (size_t)z1 * sA1 + (size_t)z2 * sA2;
    const unsigned short* Wb = W + (size_t)z1 * sW1 + (size_t)z2 * sW2;
    size_t coff = (size_t)z1 * sC1 + (size_t)z2 * sC2;
    int tid = threadIdx.x;
    int lane = tid & 63, wave = tid >> 6;
    int wm = wave & 1, wn = wave >> 1;
    int l16 = lane & 15, quad = lane >> 4;
    int m0 = blockIdx.y * 64 + wm * 32;
    int n0 = blockIdx.x * 64 + wn * 32;

    floatx4 acc00 = {0,0,0,0}, acc01 = {0,0,0,0}, acc10 = {0,0,0,0}, acc11 = {0,0,0,0};
    const unsigned short* a0p = Ab + (size_t)(m0 + l16) * lda + quad * 8;
    const unsigned short* a1p = a0p + (size_t)16 * lda;
    const unsigned short* b0p = Wb + (size_t)(n0 + l16) * ldw + quad * 8;
    const unsigned short* b1p = b0p + (size_t)16 * ldw;

    for (int kk = 0; kk < K; kk += 32) {
        short8 a0 = *(const short8*)(a0p + kk);
        short8 a1 = *(const short8*)(a1p + kk);
        short8 b0 = *(const short8*)(b0p + kk);
        short8 b1 = *(const short8*)(b1p + kk);
        acc00 = __builtin_amdgcn_mfma_f32_16x16x32_bf16(a0, b0, acc00, 0, 0, 0);
        acc01 = __builtin_amdgcn_mfma_f32_16x16x32_bf16(a0, b1, acc01, 0, 0, 0);
        acc10 = __builtin_amdgcn_mfma_f32_16x16x32_bf16(a1, b0, acc10, 0, 0, 0);
        acc11 = __builtin_amdgcn_mfma_f32_16x16x32_bf16(a1, b1, acc11, 0, 0, 0);
    }
    floatx4 accs[2][2] = {{acc00, acc01}, {acc10, acc11}};
    for (int mt = 0; mt < 2; ++mt)
        for (int nt = 0; nt < 2; ++nt) {
            int gn = n0 + nt * 16 + l16;
            float bb = bias ? bias[gn] : 0.0f;
            c_scatter(accs[mt][nt], m0 + mt * 16 + quad * 4, gn, coff, ldc,
                      alpha, bb, mode, relu, Tp, Cv, Cv2, Cv3);
        }
}

// ---------------------------------------------------------------------------
// bf16 MFMA GEMM, 128x128 block tile (single batch). 4 waves, each 64x64 =
// 4x4 MFMA tiles. Per K-step: 16 MFMA vs 8 loads. acc=64 VGPR; cap 170 via
// launch_bounds so no spill and 3 waves/SIMD.
__global__ __launch_bounds__(256, 3) void gemm128_bf16(
    const unsigned short* __restrict__ A, const unsigned short* __restrict__ W,
    const float* __restrict__ bias, void* __restrict__ Cv, void* __restrict__ Cv2,
    void* __restrict__ Cv3,
    int K, int lda, int ldw, int ldc,
    float alpha, int mode, int relu, int Tp) {
    int tid = threadIdx.x;
    int lane = tid & 63, wave = tid >> 6;
    int wm = wave & 1, wn = wave >> 1;
    int l16 = lane & 15, quad = lane >> 4;
    int m0 = blockIdx.y * 128 + wm * 64;
    int n0 = blockIdx.x * 128 + wn * 64;

    floatx4 acc[4][4] = {};
    const unsigned short* ap = A + (size_t)(m0 + l16) * lda + quad * 8;
    const unsigned short* bp = W + (size_t)(n0 + l16) * ldw + quad * 8;

    for (int kk = 0; kk < K; kk += 32) {
        short8 a[4], b[4];
        for (int mt = 0; mt < 4; ++mt)
            a[mt] = *(const short8*)(ap + (size_t)mt * 16 * lda + kk);
        for (int nt = 0; nt < 4; ++nt)
            b[nt] = *(const short8*)(bp + (size_t)nt * 16 * ldw + kk);
        for (int mt = 0; mt < 4; ++mt)
            for (int nt = 0; nt < 4; ++nt)
                acc[mt][nt] = __builtin_amdgcn_mfma_f32_16x16x32_bf16(a[mt], b[nt], acc[mt][nt], 0, 0, 0);
    }
    for (int mt = 0; mt < 4; ++mt)
        for (int nt = 0; nt < 4; ++nt) {
            int gn = n0 + nt * 16 + l16;
            float bb = bias ? bias[gn] : 0.0f;
            c_scatter(acc[mt][nt], m0 + mt * 16 + quad * 4, gn, 0, ldc,
                      alpha, bb, mode, relu, Tp, Cv, Cv2, Cv3);
        }
}

// ---------------------------------------------------------------------------
// Fused scores+softmax -> bf16 probs, transposed-MFMA, spill-free split:
// Block = 256 threads = 4 waves. All waves share the same 16 rows i of one
// (b,h); wave w owns j in [w*128, (w+1)*128). launch_bounds(256,3) caps VGPR
// at ~170 (need ~130) -> no scratch spill, 3 waves/SIMD.
template <int NL, bool EM>
__global__ __launch_bounds__(256, 3) void relsoft(
    const unsigned short* __restrict__ uR,   // (B,H,NL,T,HD) bf16
    const unsigned short* __restrict__ kB,   // (B,H,T,HD) bf16
    const float* __restrict__ em,            // (B,NL,T,T) f32 or null
    const unsigned char* __restrict__ pad,   // (B,T,T) or null
    unsigned short* __restrict__ P) {        // (B,H,T,T) bf16
    int id = blockIdx.x;
    // XCD swizzle: h-siblings (same b,it) share id%8 -> same XCD L2 for em reuse
    int c = id & 7, h = (id >> 3) & 7, g = id >> 6;
    int u = g * 8 + c;                 // 0..255
    int b = u >> 5, it = u & 31;
    int bh = b * Hn + h;
    int wave = threadIdx.x >> 6, lane = threadIdx.x & 63;
    int l16 = lane & 15, quad = lane >> 4;
    int i = it * 16 + l16;

    // u fragments for the block's 16 rows (same for all 4 waves)
    short8 uf[NL][2];
    const unsigned short* ub = uR + (size_t)bh * NL * Tn * HDn + (size_t)i * HDn + quad * 8;
    for (int l = 0; l < NL; ++l) {
        uf[l][0] = *(const short8*)(ub + (size_t)l * Tn * HDn);
        uf[l][1] = *(const short8*)(ub + (size_t)l * Tn * HDn + 32);
    }
    const unsigned short* kp0 = kB + (size_t)bh * Tn * HDn + (size_t)l16 * HDn + quad * 8;
    const float* emB = EM ? (em + ((size_t)b * NL * Tn + i) * Tn) : nullptr;

    const int JC = Tn / 64;            // 8 j-chunks of 16 per wave
    floatx4 sacc[JC];
    for (int jc = 0; jc < JC; ++jc) {
        int jt = wave * JC + jc;
        const unsigned short* kp = kp0 + (size_t)jt * 16 * HDn;
        short8 k0 = *(const short8*)(kp);
        short8 k1 = *(const short8*)(kp + 32);
        if (EM) {
            floatx4 s = {0, 0, 0, 0};
            for (int l = 0; l < NL; ++l) {
                floatx4 e4 = *(const floatx4*)(emB + (size_t)l * Tn * Tn + jt * 16 + quad * 4);
                floatx4 gacc = {0, 0, 0, 0};
                gacc = __builtin_amdgcn_mfma_f32_16x16x32_bf16(k0, uf[l][0], gacc, 0, 0, 0);
                gacc = __builtin_amdgcn_mfma_f32_16x16x32_bf16(k1, uf[l][1], gacc, 0, 0, 0);
                s += e4 * gacc;
            }
            sacc[jc] = s;
        } else {
            floatx4 gacc = {0, 0, 0, 0};
            gacc = __builtin_amdgcn_mfma_f32_16x16x32_bf16(k0, uf[0][0], gacc, 0, 0, 0);
            gacc = __builtin_amdgcn_mfma_f32_16x16x32_bf16(k1, uf[0][1], gacc, 0, 0, 0);
            sacc[jc] = gacc;
        }
    }

    // scale + pad mask + per-wave row max
    float mx = -3.0e38f;
    for (int jc = 0; jc < JC; ++jc) {
        int jt = wave * JC + jc;
        floatx4 v = sacc[jc] * SCALE;
        if (EM) {
            unsigned int pu = *(const unsigned int*)(pad + ((size_t)b * Tn + i) * Tn + jt * 16 + quad * 4);
            if (pu) {
                if (pu & 0x000000FFu) v[0] = -1.0e9f;
                if (pu & 0x0000FF00u) v[1] = -1.0e9f;
                if (pu & 0x00FF0000u) v[2] = -1.0e9f;
                if (pu & 0xFF000000u) v[3] = -1.0e9f;
            }
        }
        sacc[jc] = v;
        mx = fmaxf(mx, fmaxf(fmaxf(v[0], v[1]), fmaxf(v[2], v[3])));
    }
    mx = fmaxf(mx, __shfl_xor(mx, 16, 64));
    mx = fmaxf(mx, __shfl_xor(mx, 32, 64));

    __shared__ float redm[4][16];
    __shared__ float reds[4][16];
    if (quad == 0) redm[wave][l16] = mx;
    __syncthreads();
    mx = fmaxf(fmaxf(redm[0][l16], redm[1][l16]), fmaxf(redm[2][l16], redm[3][l16]));

    float sum = 0.0f;
    for (int jc = 0; jc < JC; ++jc) {
        floatx4 v = sacc[jc];
        v[0] = __expf(v[0] - mx); v[1] = __expf(v[1] - mx);
        v[2] = __expf(v[2] - mx); v[3] = __expf(v[3] - mx);
        sacc[jc] = v;
        sum += v[0] + v[1] + v[2] + v[3];
    }
    sum += __shfl_xor(sum, 16, 64);
    sum += __shfl_xor(sum, 32, 64);
    if (quad == 0) reds[wave][l16] = sum;
    __syncthreads();
    sum = (reds[0][l16] + reds[1][l16]) + (reds[2][l16] + reds[3][l16]);
    float inv = 1.0f / sum;

    unsigned short* prow = P + (size_t)bh * Tn * Tn + (size_t)i * Tn;
    for (int jc = 0; jc < JC; ++jc) {
        int jt = wave * JC + jc;
        floatx4 v = sacc[jc];
        ushort4 o;
        o.x = f2b(v[0] * inv); o.y = f2b(v[1] * inv);
        o.z = f2b(v[2] * inv); o.w = f2b(v[3] * inv);
        *(ushort4*)(prow + jt * 16 + quad * 4) = o;
    }
}

// ---------------------------------------------------------------------------
// LayerNorm over D=512: out = (a[row] + b2[row] - mean)/sqrt(var+eps)*s + bb
__global__ __launch_bounds__(256) void ln_kernel(
    const float* __restrict__ a, int a_trans, const float* __restrict__ b2,
    const float* __restrict__ s, const float* __restrict__ bb,
    float* __restrict__ outF, int out_trans, unsigned short* __restrict__ outB) {
    int row = blockIdx.x;            // b*Tn + t
    int b = row >> 9, t = row & (Tn - 1);
    int tid = threadIdx.x;
    size_t ia = a_trans ? ((size_t)(t * Bn + b)) * Dn : (size_t)row * Dn;
    size_t ir = (size_t)row * Dn;
    float x0 = a[ia + tid];
    float x1 = a[ia + tid + 256];
    if (b2) { x0 += b2[ir + tid]; x1 += b2[ir + tid + 256]; }
    float s1 = x0 + x1, s2 = x0 * x0 + x1 * x1;
    for (int off = 32; off; off >>= 1) {
        s1 += __shfl_xor(s1, off, 64);
        s2 += __shfl_xor(s2, off, 64);
    }
    __shared__ float red[2][4];
    int wave = tid >> 6, lane = tid & 63;
    if (lane == 0) { red[0][wave] = s1; red[1][wave] = s2; }
    __syncthreads();
    float ts1 = red[0][0] + red[0][1] + red[0][2] + red[0][3];
    float ts2 = red[1][0] + red[1][1] + red[1][2] + red[1][3];
    float mean = ts1 * (1.0f / Dn);
    float var = ts2 * (1.0f / Dn) - mean * mean;
    float rs = rsqrtf(var + 1e-5f);
    float y0 = (x0 - mean) * rs * s[tid] + bb[tid];
    float y1 = (x1 - mean) * rs * s[tid + 256] + bb[tid + 256];
    size_t io = out_trans ? ((size_t)(t * Bn + b)) * Dn : ir;
    if (outF) { outF[io + tid] = y0; outF[io + tid + 256] = y1; }
    if (outB) { outB[ir + tid] = f2b(y0); outB[ir + tid + 256] = f2b(y1); }
}

// ---------------------------------------------------------------------------
extern "C" void kernel_launch(void* const* d_in, const int* in_sizes, int n_in,
                              void* d_out, int out_size, void* d_ws, size_t ws_size,
                              hipStream_t stream) {
    const float* tgt      = (const float*)d_in[0];
    const float* em       = (const float*)d_in[1];
    const unsigned char* pad = (const unsigned char*)d_in[2];
    const float* memr     = (const float*)d_in[3];
    const float* sa_q_w   = (const float*)d_in[4];
    const float* sa_q_b   = (const float*)d_in[5];
    const float* sa_k_w   = (const float*)d_in[6];
    const float* sa_k_b   = (const float*)d_in[7];
    const float* sa_v_w   = (const float*)d_in[8];
    const float* sa_v_b   = (const float*)d_in[9];
    const float* sa_rel   = (const float*)d_in[10];
    const float* sa_out_w = (const float*)d_in[11];
    const float* sa_out_b = (const float*)d_in[12];
    const float* ca_in_w  = (const float*)d_in[13];
    const float* ca_in_b  = (const float*)d_in[14];
    const float* ca_out_w = (const float*)d_in[15];
    const float* ca_out_b = (const float*)d_in[16];
    const float* lin1_w   = (const float*)d_in[17];
    const float* lin1_b   = (const float*)d_in[18];
    const float* lin2_w   = (const float*)d_in[19];
    const float* lin2_b   = (const float*)d_in[20];
    const float* ln1_s    = (const float*)d_in[21];
    const float* ln1_b    = (const float*)d_in[22];
    const float* ln2_s    = (const float*)d_in[23];
    const float* ln2_b    = (const float*)d_in[24];
    const float* ln3_s    = (const float*)d_in[25];
    const float* ln3_b    = (const float*)d_in[26];

    const size_t BT = (size_t)Bn * Tn;   // 4096
    const size_t Q  = 1 << 18;           // 256K elems

    // ---- workspace carve-out ----
    char* ws = (char*)d_ws;
    size_t off = 0;
    auto alloc = [&](size_t bytes) -> char* {
        char* p = ws + off;
        off += (bytes + 255) & ~(size_t)255;
        return p;
    };
    unsigned short* xb   = (unsigned short*)alloc(BT * Dn * 2);
    unsigned short* mb   = (unsigned short*)alloc(BT * Dn * 2);
    unsigned short* wall = (unsigned short*)alloc((16 * Q + Ln * HDn * HDn) * 2);
    float*          bqkv = (float*)alloc(3 * Dn * 4);
    unsigned short* qb   = (unsigned short*)alloc(BT * Dn * 2);          // (B,H,T,HD)
    unsigned short* kb   = (unsigned short*)alloc(BT * Dn * 2);          // (B,H,T,HD)
    unsigned short* vtb  = (unsigned short*)alloc(BT * Dn * 2);          // (B,H,HD,T)
    unsigned short* ur   = (unsigned short*)alloc((size_t)Bn * Hn * Ln * Tn * HDn * 2);
    unsigned short* pb   = (unsigned short*)alloc((size_t)Bn * Hn * Tn * Tn * 2); // 32MB probs
    unsigned short* ob   = (unsigned short*)alloc(BT * Dn * 2);
    float*          t2f  = (float*)alloc(BT * Dn * 4);
    float*          x1f  = (float*)alloc(BT * Dn * 4);
    unsigned short* x1b  = (unsigned short*)alloc(BT * Dn * 2);
    float*          x2f  = (float*)alloc(BT * Dn * 4);
    unsigned short* x2b  = (unsigned short*)alloc(BT * Dn * 2);
    unsigned short* hid  = (unsigned short*)alloc(BT * Fn * 2);
    (void)ws_size; (void)in_sizes; (void)n_in; (void)out_size;

    // arena views
    unsigned short* wqkv = wall;
    unsigned short* wsao = wall + 3 * Q;
    unsigned short* wcain = wall + 4 * Q;
    unsigned short* wcao = wall + 7 * Q;
    unsigned short* wlin1 = wall + 8 * Q;
    unsigned short* wlin2 = wall + 12 * Q;
    unsigned short* wrel = wall + 16 * Q;

    auto gemm = [&](const unsigned short* A, const unsigned short* W, const float* bias,
                    void* C, void* C2, void* C3, int M, int N, int K, int lda, int ldw, int ldc,
                    long sA1, long sA2, long sW1, long sW2, long sC1, long sC2,
                    int zdiv, int batches, float alpha, int mode, int relu, int Tp) {
        dim3 g(N / 64, M / 64, batches);
        gemm_bf16<<<g, 256, 0, stream>>>(A, W, bias, C, C2, C3, M, N, K, lda, ldw, ldc,
                                         sA1, sA2, sW1, sW2, sC1, sC2, zdiv,
                                         alpha, mode, relu, Tp);
    };
    auto gemm128 = [&](const unsigned short* A, const unsigned short* W, const float* bias,
                       void* C, void* C2, void* C3, int M, int N, int K,
                       int lda, int ldw, int ldc, float alpha, int mode, int relu, int Tp) {
        dim3 g(N / 128, M / 128, 1);
        gemm128_bf16<<<g, 256, 0, stream>>>(A, W, bias, C, C2, C3, K, lda, ldw, ldc,
                                            alpha, mode, relu, Tp);
    };

    // ---- prep ----
    to_rows_bf16<<<dim3((BT * Dn + 255) / 256), 256, 0, stream>>>(tgt, xb, Tn);
    to_rows_bf16<<<dim3((BT * Dn + 255) / 256), 256, 0, stream>>>(memr, mb, Sn);
    conv_all<<<dim3((16 * Q + Ln * HDn * HDn + 3 * Dn + 255) / 256), 256, 0, stream>>>(
        sa_q_w, sa_k_w, sa_v_w, sa_out_w, ca_in_w, ca_out_w, lin1_w, lin2_w, sa_rel,
        sa_q_b, sa_k_b, sa_v_b, wall, bqkv);

    // ---- self-attention ----
    // fused q,k,v: (B,H,T,HD) x2 + v as (B,H,HD,T)
    gemm128(xb, wqkv, bqkv, qb, kb, vtb, (int)BT, 3 * Dn, Dn, Dn, Dn, 0, 1.0f, 4, 0, Tn);
    // uR[b,h,l] = q[b,h] @ R_l^T  (batched over B*H*L)
    gemm(qb, wrel, nullptr, ur, nullptr, nullptr, Tn, HDn, HDn, HDn, HDn, HDn,
         (long)Tn * HDn, 0, 0, (long)HDn * HDn, (long)Ln * Tn * HDn, (long)Tn * HDn,
         Ln, Bn * Hn * Ln, 1.0f, 1, 0, 0);
    // fused rel-scores + em + scale + pad + softmax -> bf16 P
    relsoft<Ln, true><<<dim3(2048), 256, 0, stream>>>(ur, kb, em, pad, pb);
    // O = P @ V
    gemm(pb, vtb, nullptr, ob, nullptr, nullptr, Tn, HDn, Tn, Tn, Tn, Dn,
         (long)Hn * Tn * Tn, (long)Tn * Tn, (long)Hn * HDn * Tn, (long)HDn * Tn,
         (long)Tn * Dn, 64, Hn, Bn * Hn, 1.0f, 1, 0, 0);
    gemm128(ob, wsao, sa_out_b, t2f, nullptr, nullptr, (int)BT, Dn, Dn, Dn, Dn, Dn,
            1.0f, 0, 0, 0);
    ln_kernel<<<dim3((int)BT), 256, 0, stream>>>(tgt, 1, t2f, ln1_s, ln1_b, x1f, 0, x1b);

    // ---- cross-attention ----
    gemm128(x1b, wcain, ca_in_b, qb, nullptr, nullptr, (int)BT, Dn, Dn, Dn, Dn, 0,
            1.0f, 2, 0, Tn);
    // fused k,v from memory
    gemm128(mb, wcain + (size_t)Dn * Dn, ca_in_b + Dn, kb, vtb, nullptr, (int)BT, 2 * Dn, Dn,
            Dn, Dn, 0, 1.0f, 5, 0, Sn);
    // fused qk^T + scale + softmax -> bf16 P
    relsoft<1, false><<<dim3(2048), 256, 0, stream>>>(qb, kb, nullptr, nullptr, pb);
    gemm(pb, vtb, nullptr, ob, nullptr, nullptr, Tn, HDn, Sn, Sn, Sn, Dn,
         (long)Hn * Tn * Sn, (long)Tn * Sn, (long)Hn * HDn * Sn, (long)HDn * Sn,
         (long)Tn * Dn, 64, Hn, Bn * Hn, 1.0f, 1, 0, 0);
    gemm128(ob, wcao, ca_out_b, t2f, nullptr, nullptr, (int)BT, Dn, Dn, Dn, Dn, Dn,
            1.0f, 0, 0, 0);
    ln_kernel<<<dim3((int)BT), 256, 0, stream>>>(x1f, 0, t2f, ln2_s, ln2_b, x2f, 0, x2b);

    // ---- FFN ----
    gemm128(x2b, wlin1, lin1_b, hid, nullptr, nullptr, (int)BT, Fn, Dn, Dn, Dn, Fn,
            1.0f, 1, 1, 0);
    gemm128(hid, wlin2, lin2_b, t2f, nullptr, nullptr, (int)BT, Dn, Fn, Fn, Fn, Dn,
            1.0f, 0, 0, 0);
    ln_kernel<<<dim3((int)BT), 256, 0, stream>>>(x2f, 0, t2f, ln3_s, ln3_b, (float*)d_out, 1, nullptr);
}

// Round 6
// 790.451 us; speedup vs baseline: 1.4090x; 1.4090x over previous
//
#include <hip/hip_runtime.h>

// Problem constants
#define Tn 512
#define Sn 512
#define Bn 8
#define Dn 512
#define Hn 8
#define HDn 64
#define Ln 8
#define Fn 2048
#define SCALE 0.125f

typedef short short8 __attribute__((ext_vector_type(8)));
typedef float floatx4 __attribute__((ext_vector_type(4)));

__device__ __forceinline__ unsigned short f2b(float f) {
    unsigned int u = __float_as_uint(f);
    u += 0x7FFFu + ((u >> 16) & 1u);   // round-to-nearest-even
    return (unsigned short)(u >> 16);
}

// ---------------------------------------------------------------------------
// Prep: (T,B,D) f32 -> (B*T, D) bf16 rows
__global__ __launch_bounds__(256) void to_rows_bf16(const float* __restrict__ in,
                                                    unsigned short* __restrict__ out, int T_) {
    size_t n = (size_t)blockIdx.x * 256 + threadIdx.x;
    size_t total = (size_t)T_ * Bn * Dn;
    if (n >= total) return;
    int d = (int)(n & (Dn - 1));
    size_t rt = n >> 9;              // Dn = 512
    int t = (int)(rt % T_);
    int b = (int)(rt / T_);
    out[n] = f2b(in[((size_t)t * Bn + b) * Dn + d]);
}

// ---------------------------------------------------------------------------
// One-shot weight conversion into a packed bf16 arena + concatenated qkv bias.
// Arena layout (units of 256K = 1<<18 elems): [0..3):qkv  [3]:sao  [4..7):cain
// [7]:cao  [8..12):lin1  [12..16):lin2  [16]:rel(32K)
__global__ __launch_bounds__(256) void conv_all(
    const float* __restrict__ qw, const float* __restrict__ kw, const float* __restrict__ vw,
    const float* __restrict__ sow, const float* __restrict__ ciw, const float* __restrict__ cow,
    const float* __restrict__ l1w, const float* __restrict__ l2w, const float* __restrict__ rel,
    const float* __restrict__ qbias, const float* __restrict__ kbias, const float* __restrict__ vbias,
    unsigned short* __restrict__ wall, float* __restrict__ bqkv) {
    const int Q = 1 << 18;
    const int total = 16 * Q + Ln * HDn * HDn;   // 4227072
    int i = blockIdx.x * 256 + threadIdx.x;
    if (i < total) {
        int seg = i >> 18, r = i & (Q - 1);
        float v;
        if (seg < 3)       v = (seg == 0 ? qw : (seg == 1 ? kw : vw))[r];
        else if (seg == 3) v = sow[r];
        else if (seg < 7)  v = ciw[(size_t)(seg - 4) * Q + r];
        else if (seg == 7) v = cow[r];
        else if (seg < 12) v = l1w[(size_t)(seg - 8) * Q + r];
        else if (seg < 16) v = l2w[(size_t)(seg - 12) * Q + r];
        else               v = rel[r];
        wall[i] = f2b(v);
    }
    int j = i - total;
    if (j >= 0 && j < 3 * Dn)
        bqkv[j] = (j < Dn ? qbias[j] : (j < 2 * Dn ? kbias[j - Dn] : vbias[j - 2 * Dn]));
}

// ---------------------------------------------------------------------------
// Shared epilogue: scatter one 16x16 C tile per (mt,nt) per mode.
// mode 0: f32 row-major   1: bf16 row-major   2: bf16 heads (B,H,T,HD)
// mode 3: bf16 headsT (B,H,HD,T)
// mode 4: fused qkv split: gn<512->Cv heads, <1024->Cv2 heads, else Cv3 headsT
// mode 5: fused kv  split: gn<512->Cv heads, else Cv2 headsT
__device__ __forceinline__ void c_scatter(
    floatx4 v, int gm, int gn, size_t coff, int ldc, float alpha, float bb,
    int mode, int relu, int Tp, void* Cv, void* Cv2, void* Cv3) {
    for (int r = 0; r < 4; ++r) {
        float val = v[r] * alpha + bb;
        if (relu) val = fmaxf(val, 0.0f);
        int m = gm + r;
        if (mode == 0) {
            ((float*)Cv)[coff + (size_t)m * ldc + gn] = val;
        } else if (mode == 1) {
            ((unsigned short*)Cv)[coff + (size_t)m * ldc + gn] = f2b(val);
        } else if (mode == 2) {
            int bq = m / Tp, t = m - bq * Tp;
            ((unsigned short*)Cv)[(((size_t)(bq * Hn + (gn >> 6)) * Tp + t) << 6) + (gn & 63)] = f2b(val);
        } else if (mode == 3) {
            int bq = m / Tp, t = m - bq * Tp;
            ((unsigned short*)Cv)[((size_t)(bq * Hn + (gn >> 6)) * 64 + (gn & 63)) * Tp + t] = f2b(val);
        } else if (mode == 4) {
            int sel = gn >> 9, g2 = gn & 511;
            int bq = m / Tp, t = m - bq * Tp;
            int hh = g2 >> 6, dd = g2 & 63;
            if (sel == 0)
                ((unsigned short*)Cv)[(((size_t)(bq * Hn + hh) * Tp + t) << 6) + dd] = f2b(val);
            else if (sel == 1)
                ((unsigned short*)Cv2)[(((size_t)(bq * Hn + hh) * Tp + t) << 6) + dd] = f2b(val);
            else
                ((unsigned short*)Cv3)[((size_t)(bq * Hn + hh) * 64 + dd) * Tp + t] = f2b(val);
        } else { // mode 5
            int sel = gn >> 9, g2 = gn & 511;
            int bq = m / Tp, t = m - bq * Tp;
            int hh = g2 >> 6, dd = g2 & 63;
            if (sel == 0)
                ((unsigned short*)Cv)[(((size_t)(bq * Hn + hh) * Tp + t) << 6) + dd] = f2b(val);
            else
                ((unsigned short*)Cv2)[((size_t)(bq * Hn + hh) * 64 + dd) * Tp + t] = f2b(val);
        }
    }
}

// ---------------------------------------------------------------------------
// Batched bf16 MFMA GEMM, 64x64 block tile (for small-N / heavily-batched).
__global__ __launch_bounds__(256) void gemm_bf16(
    const unsigned short* __restrict__ A, const unsigned short* __restrict__ W,
    const float* __restrict__ bias, void* __restrict__ Cv, void* __restrict__ Cv2,
    void* __restrict__ Cv3,
    int M, int N, int K, int lda, int ldw, int ldc,
    long sA1, long sA2, long sW1, long sW2, long sC1, long sC2, int zdiv,
    float alpha, int mode, int relu, int Tp) {
    int z = blockIdx.z;
    int z1 = z / zdiv, z2 = z - z1 * zdiv;
    const unsigned short* Ab = A + (size_t)z1 * sA1 + (size_t)z2 * sA2;
    const unsigned short* Wb = W + (size_t)z1 * sW1 + (size_t)z2 * sW2;
    size_t coff = (size_t)z1 * sC1 + (size_t)z2 * sC2;
    int tid = threadIdx.x;
    int lane = tid & 63, wave = tid >> 6;
    int wm = wave & 1, wn = wave >> 1;
    int l16 = lane & 15, quad = lane >> 4;
    int m0 = blockIdx.y * 64 + wm * 32;
    int n0 = blockIdx.x * 64 + wn * 32;

    floatx4 acc00 = {0,0,0,0}, acc01 = {0,0,0,0}, acc10 = {0,0,0,0}, acc11 = {0,0,0,0};
    const unsigned short* a0p = Ab + (size_t)(m0 + l16) * lda + quad * 8;
    const unsigned short* a1p = a0p + (size_t)16 * lda;
    const unsigned short* b0p = Wb + (size_t)(n0 + l16) * ldw + quad * 8;
    const unsigned short* b1p = b0p + (size_t)16 * ldw;

    for (int kk = 0; kk < K; kk += 32) {
        short8 a0 = *(const short8*)(a0p + kk);
        short8 a1 = *(const short8*)(a1p + kk);
        short8 b0 = *(const short8*)(b0p + kk);
        short8 b1 = *(const short8*)(b1p + kk);
        acc00 = __builtin_amdgcn_mfma_f32_16x16x32_bf16(a0, b0, acc00, 0, 0, 0);
        acc01 = __builtin_amdgcn_mfma_f32_16x16x32_bf16(a0, b1, acc01, 0, 0, 0);
        acc10 = __builtin_amdgcn_mfma_f32_16x16x32_bf16(a1, b0, acc10, 0, 0, 0);
        acc11 = __builtin_amdgcn_mfma_f32_16x16x32_bf16(a1, b1, acc11, 0, 0, 0);
    }
    floatx4 accs[2][2] = {{acc00, acc01}, {acc10, acc11}};
    for (int mt = 0; mt < 2; ++mt)
        for (int nt = 0; nt < 2; ++nt) {
            int gn = n0 + nt * 16 + l16;
            float bb = bias ? bias[gn] : 0.0f;
            c_scatter(accs[mt][nt], m0 + mt * 16 + quad * 4, gn, coff, ldc,
                      alpha, bb, mode, relu, Tp, Cv, Cv2, Cv3);
        }
}

// ---------------------------------------------------------------------------
// bf16 MFMA GEMM, 128x128 block tile (single batch). 4 waves, each 64x64 =
// 4x4 MFMA tiles. Per K-step: 16 MFMA vs 8 loads.
__global__ __launch_bounds__(256, 3) void gemm128_bf16(
    const unsigned short* __restrict__ A, const unsigned short* __restrict__ W,
    const float* __restrict__ bias, void* __restrict__ Cv, void* __restrict__ Cv2,
    void* __restrict__ Cv3,
    int K, int lda, int ldw, int ldc,
    float alpha, int mode, int relu, int Tp) {
    int tid = threadIdx.x;
    int lane = tid & 63, wave = tid >> 6;
    int wm = wave & 1, wn = wave >> 1;
    int l16 = lane & 15, quad = lane >> 4;
    int m0 = blockIdx.y * 128 + wm * 64;
    int n0 = blockIdx.x * 128 + wn * 64;

    floatx4 acc[4][4] = {};
    const unsigned short* ap = A + (size_t)(m0 + l16) * lda + quad * 8;
    const unsigned short* bp = W + (size_t)(n0 + l16) * ldw + quad * 8;

    for (int kk = 0; kk < K; kk += 32) {
        short8 a[4], b[4];
        for (int mt = 0; mt < 4; ++mt)
            a[mt] = *(const short8*)(ap + (size_t)mt * 16 * lda + kk);
        for (int nt = 0; nt < 4; ++nt)
            b[nt] = *(const short8*)(bp + (size_t)nt * 16 * ldw + kk);
        for (int mt = 0; mt < 4; ++mt)
            for (int nt = 0; nt < 4; ++nt)
                acc[mt][nt] = __builtin_amdgcn_mfma_f32_16x16x32_bf16(a[mt], b[nt], acc[mt][nt], 0, 0, 0);
    }
    for (int mt = 0; mt < 4; ++mt)
        for (int nt = 0; nt < 4; ++nt) {
            int gn = n0 + nt * 16 + l16;
            float bb = bias ? bias[gn] : 0.0f;
            c_scatter(acc[mt][nt], m0 + mt * 16 + quad * 4, gn, 0, ldc,
                      alpha, bb, mode, relu, Tp, Cv, Cv2, Cv3);
        }
}

// ---------------------------------------------------------------------------
// Fused scores+softmax -> bf16 probs, transposed-MFMA, spill-free split:
// Block = 256 threads = 4 waves. All waves share the same 16 rows i of one
// (b,h); wave w owns j in [w*128, (w+1)*128).
// NO waves/EU cap (R5 lesson: cap => wholesale scratch spill). Register
// control instead via unroll(disable) on the jc loop (R4 lesson: full unroll
// of jc hoisted 8 iterations of operands past 256 VGPRs).
template <int NL, bool EM>
__global__ __launch_bounds__(256) void relsoft(
    const unsigned short* __restrict__ uR,   // (B,H,NL,T,HD) bf16
    const unsigned short* __restrict__ kB,   // (B,H,T,HD) bf16
    const float* __restrict__ em,            // (B,NL,T,T) f32 or null
    const unsigned char* __restrict__ pad,   // (B,T,T) or null
    unsigned short* __restrict__ P) {        // (B,H,T,T) bf16
    int id = blockIdx.x;
    // XCD swizzle: h-siblings (same b,it) share id%8 -> same XCD L2 for em reuse
    int c = id & 7, h = (id >> 3) & 7, g = id >> 6;
    int u = g * 8 + c;                 // 0..255
    int b = u >> 5, it = u & 31;
    int bh = b * Hn + h;
    int wave = threadIdx.x >> 6, lane = threadIdx.x & 63;
    int l16 = lane & 15, quad = lane >> 4;
    int i = it * 16 + l16;

    // u fragments for the block's 16 rows (same for all 4 waves)
    short8 uf[NL][2];
    const unsigned short* ub = uR + (size_t)bh * NL * Tn * HDn + (size_t)i * HDn + quad * 8;
    for (int l = 0; l < NL; ++l) {
        uf[l][0] = *(const short8*)(ub + (size_t)l * Tn * HDn);
        uf[l][1] = *(const short8*)(ub + (size_t)l * Tn * HDn + 32);
    }
    const unsigned short* kp0 = kB + (size_t)bh * Tn * HDn + (size_t)l16 * HDn + quad * 8;
    const float* emB = EM ? (em + ((size_t)b * NL * Tn + i) * Tn) : nullptr;

    const int JC = Tn / 64;            // 8 j-chunks of 16 per wave
    floatx4 sacc[JC];
#pragma clang loop unroll(disable)
    for (int jc = 0; jc < JC; ++jc) {
        int jt = wave * JC + jc;
        const unsigned short* kp = kp0 + (size_t)jt * 16 * HDn;
        short8 k0 = *(const short8*)(kp);
        short8 k1 = *(const short8*)(kp + 32);
        if (EM) {
            floatx4 s = {0, 0, 0, 0};
#pragma unroll
            for (int l = 0; l < NL; ++l) {
                floatx4 e4 = *(const floatx4*)(emB + (size_t)l * Tn * Tn + jt * 16 + quad * 4);
                floatx4 gacc = {0, 0, 0, 0};
                gacc = __builtin_amdgcn_mfma_f32_16x16x32_bf16(k0, uf[l][0], gacc, 0, 0, 0);
                gacc = __builtin_amdgcn_mfma_f32_16x16x32_bf16(k1, uf[l][1], gacc, 0, 0, 0);
                s += e4 * gacc;
            }
            sacc[jc] = s;
        } else {
            floatx4 gacc = {0, 0, 0, 0};
            gacc = __builtin_amdgcn_mfma_f32_16x16x32_bf16(k0, uf[0][0], gacc, 0, 0, 0);
            gacc = __builtin_amdgcn_mfma_f32_16x16x32_bf16(k1, uf[0][1], gacc, 0, 0, 0);
            sacc[jc] = gacc;
        }
    }

    // scale + pad mask + per-wave row max
    float mx = -3.0e38f;
    for (int jc = 0; jc < JC; ++jc) {
        int jt = wave * JC + jc;
        floatx4 v = sacc[jc] * SCALE;
        if (EM) {
            unsigned int pu = *(const unsigned int*)(pad + ((size_t)b * Tn + i) * Tn + jt * 16 + quad * 4);
            if (pu) {
                if (pu & 0x000000FFu) v[0] = -1.0e9f;
                if (pu & 0x0000FF00u) v[1] = -1.0e9f;
                if (pu & 0x00FF0000u) v[2] = -1.0e9f;
                if (pu & 0xFF000000u) v[3] = -1.0e9f;
            }
        }
        sacc[jc] = v;
        mx = fmaxf(mx, fmaxf(fmaxf(v[0], v[1]), fmaxf(v[2], v[3])));
    }
    mx = fmaxf(mx, __shfl_xor(mx, 16, 64));
    mx = fmaxf(mx, __shfl_xor(mx, 32, 64));

    __shared__ float redm[4][16];
    __shared__ float reds[4][16];
    if (quad == 0) redm[wave][l16] = mx;
    __syncthreads();
    mx = fmaxf(fmaxf(redm[0][l16], redm[1][l16]), fmaxf(redm[2][l16], redm[3][l16]));

    float sum = 0.0f;
    for (int jc = 0; jc < JC; ++jc) {
        floatx4 v = sacc[jc];
        v[0] = __expf(v[0] - mx); v[1] = __expf(v[1] - mx);
        v[2] = __expf(v[2] - mx); v[3] = __expf(v[3] - mx);
        sacc[jc] = v;
        sum += v[0] + v[1] + v[2] + v[3];
    }
    sum += __shfl_xor(sum, 16, 64);
    sum += __shfl_xor(sum, 32, 64);
    if (quad == 0) reds[wave][l16] = sum;
    __syncthreads();
    sum = (reds[0][l16] + reds[1][l16]) + (reds[2][l16] + reds[3][l16]);
    float inv = 1.0f / sum;

    unsigned short* prow = P + (size_t)bh * Tn * Tn + (size_t)i * Tn;
    for (int jc = 0; jc < JC; ++jc) {
        int jt = wave * JC + jc;
        floatx4 v = sacc[jc];
        ushort4 o;
        o.x = f2b(v[0] * inv); o.y = f2b(v[1] * inv);
        o.z = f2b(v[2] * inv); o.w = f2b(v[3] * inv);
        *(ushort4*)(prow + jt * 16 + quad * 4) = o;
    }
}

// ---------------------------------------------------------------------------
// LayerNorm over D=512: out = (a[row] + b2[row] - mean)/sqrt(var+eps)*s + bb
__global__ __launch_bounds__(256) void ln_kernel(
    const float* __restrict__ a, int a_trans, const float* __restrict__ b2,
    const float* __restrict__ s, const float* __restrict__ bb,
    float* __restrict__ outF, int out_trans, unsigned short* __restrict__ outB) {
    int row = blockIdx.x;            // b*Tn + t
    int b = row >> 9, t = row & (Tn - 1);
    int tid = threadIdx.x;
    size_t ia = a_trans ? ((size_t)(t * Bn + b)) * Dn : (size_t)row * Dn;
    size_t ir = (size_t)row * Dn;
    float x0 = a[ia + tid];
    float x1 = a[ia + tid + 256];
    if (b2) { x0 += b2[ir + tid]; x1 += b2[ir + tid + 256]; }
    float s1 = x0 + x1, s2 = x0 * x0 + x1 * x1;
    for (int off = 32; off; off >>= 1) {
        s1 += __shfl_xor(s1, off, 64);
        s2 += __shfl_xor(s2, off, 64);
    }
    __shared__ float red[2][4];
    int wave = tid >> 6, lane = tid & 63;
    if (lane == 0) { red[0][wave] = s1; red[1][wave] = s2; }
    __syncthreads();
    float ts1 = red[0][0] + red[0][1] + red[0][2] + red[0][3];
    float ts2 = red[1][0] + red[1][1] + red[1][2] + red[1][3];
    float mean = ts1 * (1.0f / Dn);
    float var = ts2 * (1.0f / Dn) - mean * mean;
    float rs = rsqrtf(var + 1e-5f);
    float y0 = (x0 - mean) * rs * s[tid] + bb[tid];
    float y1 = (x1 - mean) * rs * s[tid + 256] + bb[tid + 256];
    size_t io = out_trans ? ((size_t)(t * Bn + b)) * Dn : ir;
    if (outF) { outF[io + tid] = y0; outF[io + tid + 256] = y1; }
    if (outB) { outB[ir + tid] = f2b(y0); outB[ir + tid + 256] = f2b(y1); }
}

// ---------------------------------------------------------------------------
extern "C" void kernel_launch(void* const* d_in, const int* in_sizes, int n_in,
                              void* d_out, int out_size, void* d_ws, size_t ws_size,
                              hipStream_t stream) {
    const float* tgt      = (const float*)d_in[0];
    const float* em       = (const float*)d_in[1];
    const unsigned char* pad = (const unsigned char*)d_in[2];
    const float* memr     = (const float*)d_in[3];
    const float* sa_q_w   = (const float*)d_in[4];
    const float* sa_q_b   = (const float*)d_in[5];
    const float* sa_k_w   = (const float*)d_in[6];
    const float* sa_k_b   = (const float*)d_in[7];
    const float* sa_v_w   = (const float*)d_in[8];
    const float* sa_v_b   = (const float*)d_in[9];
    const float* sa_rel   = (const float*)d_in[10];
    const float* sa_out_w = (const float*)d_in[11];
    const float* sa_out_b = (const float*)d_in[12];
    const float* ca_in_w  = (const float*)d_in[13];
    const float* ca_in_b  = (const float*)d_in[14];
    const float* ca_out_w = (const float*)d_in[15];
    const float* ca_out_b = (const float*)d_in[16];
    const float* lin1_w   = (const float*)d_in[17];
    const float* lin1_b   = (const float*)d_in[18];
    const float* lin2_w   = (const float*)d_in[19];
    const float* lin2_b   = (const float*)d_in[20];
    const float* ln1_s    = (const float*)d_in[21];
    const float* ln1_b    = (const float*)d_in[22];
    const float* ln2_s    = (const float*)d_in[23];
    const float* ln2_b    = (const float*)d_in[24];
    const float* ln3_s    = (const float*)d_in[25];
    const float* ln3_b    = (const float*)d_in[26];

    const size_t BT = (size_t)Bn * Tn;   // 4096
    const size_t Q  = 1 << 18;           // 256K elems

    // ---- workspace carve-out ----
    char* ws = (char*)d_ws;
    size_t off = 0;
    auto alloc = [&](size_t bytes) -> char* {
        char* p = ws + off;
        off += (bytes + 255) & ~(size_t)255;
        return p;
    };
    unsigned short* xb   = (unsigned short*)alloc(BT * Dn * 2);
    unsigned short* mb   = (unsigned short*)alloc(BT * Dn * 2);
    unsigned short* wall = (unsigned short*)alloc((16 * Q + Ln * HDn * HDn) * 2);
    float*          bqkv = (float*)alloc(3 * Dn * 4);
    unsigned short* qb   = (unsigned short*)alloc(BT * Dn * 2);          // (B,H,T,HD)
    unsigned short* kb   = (unsigned short*)alloc(BT * Dn * 2);          // (B,H,T,HD)
    unsigned short* vtb  = (unsigned short*)alloc(BT * Dn * 2);          // (B,H,HD,T)
    unsigned short* ur   = (unsigned short*)alloc((size_t)Bn * Hn * Ln * Tn * HDn * 2);
    unsigned short* pb   = (unsigned short*)alloc((size_t)Bn * Hn * Tn * Tn * 2); // 32MB probs
    unsigned short* ob   = (unsigned short*)alloc(BT * Dn * 2);
    float*          t2f  = (float*)alloc(BT * Dn * 4);
    float*          x1f  = (float*)alloc(BT * Dn * 4);
    unsigned short* x1b  = (unsigned short*)alloc(BT * Dn * 2);
    float*          x2f  = (float*)alloc(BT * Dn * 4);
    unsigned short* x2b  = (unsigned short*)alloc(BT * Dn * 2);
    unsigned short* hid  = (unsigned short*)alloc(BT * Fn * 2);
    (void)ws_size; (void)in_sizes; (void)n_in; (void)out_size;

    // arena views
    unsigned short* wqkv = wall;
    unsigned short* wsao = wall + 3 * Q;
    unsigned short* wcain = wall + 4 * Q;
    unsigned short* wcao = wall + 7 * Q;
    unsigned short* wlin1 = wall + 8 * Q;
    unsigned short* wlin2 = wall + 12 * Q;
    unsigned short* wrel = wall + 16 * Q;

    auto gemm = [&](const unsigned short* A, const unsigned short* W, const float* bias,
                    void* C, void* C2, void* C3, int M, int N, int K, int lda, int ldw, int ldc,
                    long sA1, long sA2, long sW1, long sW2, long sC1, long sC2,
                    int zdiv, int batches, float alpha, int mode, int relu, int Tp) {
        dim3 g(N / 64, M / 64, batches);
        gemm_bf16<<<g, 256, 0, stream>>>(A, W, bias, C, C2, C3, M, N, K, lda, ldw, ldc,
                                         sA1, sA2, sW1, sW2, sC1, sC2, zdiv,
                                         alpha, mode, relu, Tp);
    };
    auto gemm128 = [&](const unsigned short* A, const unsigned short* W, const float* bias,
                       void* C, void* C2, void* C3, int M, int N, int K,
                       int lda, int ldw, int ldc, float alpha, int mode, int relu, int Tp) {
        dim3 g(N / 128, M / 128, 1);
        gemm128_bf16<<<g, 256, 0, stream>>>(A, W, bias, C, C2, C3, K, lda, ldw, ldc,
                                            alpha, mode, relu, Tp);
    };

    // ---- prep ----
    to_rows_bf16<<<dim3((BT * Dn + 255) / 256), 256, 0, stream>>>(tgt, xb, Tn);
    to_rows_bf16<<<dim3((BT * Dn + 255) / 256), 256, 0, stream>>>(memr, mb, Sn);
    conv_all<<<dim3((16 * Q + Ln * HDn * HDn + 3 * Dn + 255) / 256), 256, 0, stream>>>(
        sa_q_w, sa_k_w, sa_v_w, sa_out_w, ca_in_w, ca_out_w, lin1_w, lin2_w, sa_rel,
        sa_q_b, sa_k_b, sa_v_b, wall, bqkv);

    // ---- self-attention ----
    // fused q,k,v: (B,H,T,HD) x2 + v as (B,H,HD,T)
    gemm128(xb, wqkv, bqkv, qb, kb, vtb, (int)BT, 3 * Dn, Dn, Dn, Dn, 0, 1.0f, 4, 0, Tn);
    // uR[b,h,l] = q[b,h] @ R_l^T  (batched over B*H*L)
    gemm(qb, wrel, nullptr, ur, nullptr, nullptr, Tn, HDn, HDn, HDn, HDn, HDn,
         (long)Tn * HDn, 0, 0, (long)HDn * HDn, (long)Ln * Tn * HDn, (long)Tn * HDn,
         Ln, Bn * Hn * Ln, 1.0f, 1, 0, 0);
    // fused rel-scores + em + scale + pad + softmax -> bf16 P
    relsoft<Ln, true><<<dim3(2048), 256, 0, stream>>>(ur, kb, em, pad, pb);
    // O = P @ V
    gemm(pb, vtb, nullptr, ob, nullptr, nullptr, Tn, HDn, Tn, Tn, Tn, Dn,
         (long)Hn * Tn * Tn, (long)Tn * Tn, (long)Hn * HDn * Tn, (long)HDn * Tn,
         (long)Tn * Dn, 64, Hn, Bn * Hn, 1.0f, 1, 0, 0);
    gemm128(ob, wsao, sa_out_b, t2f, nullptr, nullptr, (int)BT, Dn, Dn, Dn, Dn, Dn,
            1.0f, 0, 0, 0);
    ln_kernel<<<dim3((int)BT), 256, 0, stream>>>(tgt, 1, t2f, ln1_s, ln1_b, x1f, 0, x1b);

    // ---- cross-attention ----
    gemm128(x1b, wcain, ca_in_b, qb, nullptr, nullptr, (int)BT, Dn, Dn, Dn, Dn, 0,
            1.0f, 2, 0, Tn);
    // fused k,v from memory
    gemm128(mb, wcain + (size_t)Dn * Dn, ca_in_b + Dn, kb, vtb, nullptr, (int)BT, 2 * Dn, Dn,
            Dn, Dn, 0, 1.0f, 5, 0, Sn);
    // fused qk^T + scale + softmax -> bf16 P
    relsoft<1, false><<<dim3(2048), 256, 0, stream>>>(qb, kb, nullptr, nullptr, pb);
    gemm(pb, vtb, nullptr, ob, nullptr, nullptr, Tn, HDn, Sn, Sn, Sn, Dn,
         (long)Hn * Tn * Sn, (long)Tn * Sn, (long)Hn * HDn * Sn, (long)HDn * Sn,
         (long)Tn * Dn, 64, Hn, Bn * Hn, 1.0f, 1, 0, 0);
    gemm128(ob, wcao, ca_out_b, t2f, nullptr, nullptr, (int)BT, Dn, Dn, Dn, Dn, Dn,
            1.0f, 0, 0, 0);
    ln_kernel<<<dim3((int)BT), 256, 0, stream>>>(x1f, 0, t2f, ln2_s, ln2_b, x2f, 0, x2b);

    // ---- FFN ----
    gemm128(x2b, wlin1, lin1_b, hid, nullptr, nullptr, (int)BT, Fn, Dn, Dn, Dn, Fn,
            1.0f, 1, 1, 0);
    gemm128(hid, wlin2, lin2_b, t2f, nullptr, nullptr, (int)BT, Dn, Fn, Fn, Fn, Dn,
            1.0f, 0, 0, 0);
    ln_kernel<<<dim3((int)BT), 256, 0, stream>>>(x2f, 0, t2f, ln3_s, ln3_b, (float*)d_out, 1, nullptr);
}

// Round 7
// 665.026 us; speedup vs baseline: 1.6748x; 1.1886x over previous
//
#include <hip/hip_runtime.h>

// Problem constants
#define Tn 512
#define Sn 512
#define Bn 8
#define Dn 512
#define Hn 8
#define HDn 64
#define Ln 8
#define Fn 2048
#define SCALE 0.125f

typedef short short8 __attribute__((ext_vector_type(8)));
typedef float floatx4 __attribute__((ext_vector_type(4)));

__device__ __forceinline__ unsigned short f2b(float f) {
    unsigned int u = __float_as_uint(f);
    u += 0x7FFFu + ((u >> 16) & 1u);   // round-to-nearest-even
    return (unsigned short)(u >> 16);
}

// ---------------------------------------------------------------------------
// Prep: (T,B,D) f32 -> (B*T, D) bf16 rows
__global__ __launch_bounds__(256) void to_rows_bf16(const float* __restrict__ in,
                                                    unsigned short* __restrict__ out, int T_) {
    size_t n = (size_t)blockIdx.x * 256 + threadIdx.x;
    size_t total = (size_t)T_ * Bn * Dn;
    if (n >= total) return;
    int d = (int)(n & (Dn - 1));
    size_t rt = n >> 9;              // Dn = 512
    int t = (int)(rt % T_);
    int b = (int)(rt / T_);
    out[n] = f2b(in[((size_t)t * Bn + b) * Dn + d]);
}

// ---------------------------------------------------------------------------
// One-shot weight conversion into a packed bf16 arena + concatenated qkv bias.
// Arena layout (units of 256K = 1<<18 elems): [0..3):qkv  [3]:sao  [4..7):cain
// [7]:cao  [8..12):lin1  [12..16):lin2  [16]:rel(32K)
__global__ __launch_bounds__(256) void conv_all(
    const float* __restrict__ qw, const float* __restrict__ kw, const float* __restrict__ vw,
    const float* __restrict__ sow, const float* __restrict__ ciw, const float* __restrict__ cow,
    const float* __restrict__ l1w, const float* __restrict__ l2w, const float* __restrict__ rel,
    const float* __restrict__ qbias, const float* __restrict__ kbias, const float* __restrict__ vbias,
    unsigned short* __restrict__ wall, float* __restrict__ bqkv) {
    const int Q = 1 << 18;
    const int total = 16 * Q + Ln * HDn * HDn;   // 4227072
    int i = blockIdx.x * 256 + threadIdx.x;
    if (i < total) {
        int seg = i >> 18, r = i & (Q - 1);
        float v;
        if (seg < 3)       v = (seg == 0 ? qw : (seg == 1 ? kw : vw))[r];
        else if (seg == 3) v = sow[r];
        else if (seg < 7)  v = ciw[(size_t)(seg - 4) * Q + r];
        else if (seg == 7) v = cow[r];
        else if (seg < 12) v = l1w[(size_t)(seg - 8) * Q + r];
        else if (seg < 16) v = l2w[(size_t)(seg - 12) * Q + r];
        else               v = rel[r];
        wall[i] = f2b(v);
    }
    int j = i - total;
    if (j >= 0 && j < 3 * Dn)
        bqkv[j] = (j < Dn ? qbias[j] : (j < 2 * Dn ? kbias[j - Dn] : vbias[j - 2 * Dn]));
}

// ---------------------------------------------------------------------------
// Shared epilogue: scatter one 16x16 C tile per (mt,nt) per mode.
// mode 0: f32 row-major   1: bf16 row-major   2: bf16 heads (B,H,T,HD)
// mode 3: bf16 headsT (B,H,HD,T)
// mode 4: fused qkv split: gn<512->Cv heads, <1024->Cv2 heads, else Cv3 headsT
// mode 5: fused kv  split: gn<512->Cv heads, else Cv2 headsT
__device__ __forceinline__ void c_scatter(
    floatx4 v, int gm, int gn, size_t coff, int ldc, float alpha, float bb,
    int mode, int relu, int Tp, void* Cv, void* Cv2, void* Cv3) {
    for (int r = 0; r < 4; ++r) {
        float val = v[r] * alpha + bb;
        if (relu) val = fmaxf(val, 0.0f);
        int m = gm + r;
        if (mode == 0) {
            ((float*)Cv)[coff + (size_t)m * ldc + gn] = val;
        } else if (mode == 1) {
            ((unsigned short*)Cv)[coff + (size_t)m * ldc + gn] = f2b(val);
        } else if (mode == 2) {
            int bq = m / Tp, t = m - bq * Tp;
            ((unsigned short*)Cv)[(((size_t)(bq * Hn + (gn >> 6)) * Tp + t) << 6) + (gn & 63)] = f2b(val);
        } else if (mode == 3) {
            int bq = m / Tp, t = m - bq * Tp;
            ((unsigned short*)Cv)[((size_t)(bq * Hn + (gn >> 6)) * 64 + (gn & 63)) * Tp + t] = f2b(val);
        } else if (mode == 4) {
            int sel = gn >> 9, g2 = gn & 511;
            int bq = m / Tp, t = m - bq * Tp;
            int hh = g2 >> 6, dd = g2 & 63;
            if (sel == 0)
                ((unsigned short*)Cv)[(((size_t)(bq * Hn + hh) * Tp + t) << 6) + dd] = f2b(val);
            else if (sel == 1)
                ((unsigned short*)Cv2)[(((size_t)(bq * Hn + hh) * Tp + t) << 6) + dd] = f2b(val);
            else
                ((unsigned short*)Cv3)[((size_t)(bq * Hn + hh) * 64 + dd) * Tp + t] = f2b(val);
        } else { // mode 5
            int sel = gn >> 9, g2 = gn & 511;
            int bq = m / Tp, t = m - bq * Tp;
            int hh = g2 >> 6, dd = g2 & 63;
            if (sel == 0)
                ((unsigned short*)Cv)[(((size_t)(bq * Hn + hh) * Tp + t) << 6) + dd] = f2b(val);
            else
                ((unsigned short*)Cv2)[((size_t)(bq * Hn + hh) * 64 + dd) * Tp + t] = f2b(val);
        }
    }
}

// ---------------------------------------------------------------------------
// Batched bf16 MFMA GEMM, 64x64 block tile (heavily-batched attn GEMMs).
// K-loop unroll(2) for load ILP.
__global__ __launch_bounds__(256) void gemm_bf16(
    const unsigned short* __restrict__ A, const unsigned short* __restrict__ W,
    const float* __restrict__ bias, void* __restrict__ Cv, void* __restrict__ Cv2,
    void* __restrict__ Cv3,
    int M, int N, int K, int lda, int ldw, int ldc,
    long sA1, long sA2, long sW1, long sW2, long sC1, long sC2, int zdiv,
    float alpha, int mode, int relu, int Tp) {
    int z = blockIdx.z;
    int z1 = z / zdiv, z2 = z - z1 * zdiv;
    const unsigned short* Ab = A + (size_t)z1 * sA1 + (size_t)z2 * sA2;
    const unsigned short* Wb = W + (size_t)z1 * sW1 + (size_t)z2 * sW2;
    size_t coff = (size_t)z1 * sC1 + (size_t)z2 * sC2;
    int tid = threadIdx.x;
    int lane = tid & 63, wave = tid >> 6;
    int wm = wave & 1, wn = wave >> 1;
    int l16 = lane & 15, quad = lane >> 4;
    int m0 = blockIdx.y * 64 + wm * 32;
    int n0 = blockIdx.x * 64 + wn * 32;

    floatx4 acc00 = {0,0,0,0}, acc01 = {0,0,0,0}, acc10 = {0,0,0,0}, acc11 = {0,0,0,0};
    const unsigned short* a0p = Ab + (size_t)(m0 + l16) * lda + quad * 8;
    const unsigned short* a1p = a0p + (size_t)16 * lda;
    const unsigned short* b0p = Wb + (size_t)(n0 + l16) * ldw + quad * 8;
    const unsigned short* b1p = b0p + (size_t)16 * ldw;

#pragma unroll 2
    for (int kk = 0; kk < K; kk += 32) {
        short8 a0 = *(const short8*)(a0p + kk);
        short8 a1 = *(const short8*)(a1p + kk);
        short8 b0 = *(const short8*)(b0p + kk);
        short8 b1 = *(const short8*)(b1p + kk);
        acc00 = __builtin_amdgcn_mfma_f32_16x16x32_bf16(a0, b0, acc00, 0, 0, 0);
        acc01 = __builtin_amdgcn_mfma_f32_16x16x32_bf16(a0, b1, acc01, 0, 0, 0);
        acc10 = __builtin_amdgcn_mfma_f32_16x16x32_bf16(a1, b0, acc10, 0, 0, 0);
        acc11 = __builtin_amdgcn_mfma_f32_16x16x32_bf16(a1, b1, acc11, 0, 0, 0);
    }
    floatx4 accs[2][2] = {{acc00, acc01}, {acc10, acc11}};
    for (int mt = 0; mt < 2; ++mt)
        for (int nt = 0; nt < 2; ++nt) {
            int gn = n0 + nt * 16 + l16;
            float bb = bias ? bias[gn] : 0.0f;
            c_scatter(accs[mt][nt], m0 + mt * 16 + quad * 4, gn, coff, ldc,
                      alpha, bb, mode, relu, Tp, Cv, Cv2, Cv3);
        }
}

// ---------------------------------------------------------------------------
// bf16 MFMA GEMM, templated tile: block = 2x2 waves, each wave MT*16 x NT*16.
// Block tile = (MT*32) x (NT*32). No waves/EU cap (R5 lesson).
template <int MT, int NT>
__global__ __launch_bounds__(256) void gemmT_bf16(
    const unsigned short* __restrict__ A, const unsigned short* __restrict__ W,
    const float* __restrict__ bias, void* __restrict__ Cv, void* __restrict__ Cv2,
    void* __restrict__ Cv3,
    int K, int lda, int ldw, int ldc,
    float alpha, int mode, int relu, int Tp) {
    int tid = threadIdx.x;
    int lane = tid & 63, wave = tid >> 6;
    int wm = wave & 1, wn = wave >> 1;
    int l16 = lane & 15, quad = lane >> 4;
    int m0 = blockIdx.y * (MT * 32) + wm * (MT * 16);
    int n0 = blockIdx.x * (NT * 32) + wn * (NT * 16);

    floatx4 acc[MT][NT] = {};
    const unsigned short* ap = A + (size_t)(m0 + l16) * lda + quad * 8;
    const unsigned short* bp = W + (size_t)(n0 + l16) * ldw + quad * 8;

    for (int kk = 0; kk < K; kk += 32) {
        short8 a[MT], b[NT];
#pragma unroll
        for (int mt = 0; mt < MT; ++mt)
            a[mt] = *(const short8*)(ap + (size_t)mt * 16 * lda + kk);
#pragma unroll
        for (int nt = 0; nt < NT; ++nt)
            b[nt] = *(const short8*)(bp + (size_t)nt * 16 * ldw + kk);
#pragma unroll
        for (int mt = 0; mt < MT; ++mt)
#pragma unroll
            for (int nt = 0; nt < NT; ++nt)
                acc[mt][nt] = __builtin_amdgcn_mfma_f32_16x16x32_bf16(a[mt], b[nt], acc[mt][nt], 0, 0, 0);
    }
    for (int mt = 0; mt < MT; ++mt)
        for (int nt = 0; nt < NT; ++nt) {
            int gn = n0 + nt * 16 + l16;
            float bb = bias ? bias[gn] : 0.0f;
            c_scatter(acc[mt][nt], m0 + mt * 16 + quad * 4, gn, 0, ldc,
                      alpha, bb, mode, relu, Tp, Cv, Cv2, Cv3);
        }
}

// ---------------------------------------------------------------------------
// Fused scores+softmax -> bf16 probs, transposed-MFMA.
// Block = 256 threads = 4 waves, same 16 rows i of one (b,h); wave w owns
// j in [w*128,(w+1)*128).
// R7 structure: k fragments (l-invariant, 64 VGPR) hoisted and resident;
// l is the OUTER non-unrolled loop (live u-state = 2 frags = 8 VGPR);
// jc fully unrolled inside -> 8 independent em loads + 16 MFMA per l-step.
// ~160 live VGPRs: spill-free without any waves/EU cap.
template <int NL, bool EM>
__global__ __launch_bounds__(256) void relsoft(
    const unsigned short* __restrict__ uR,   // (B,H,NL,T,HD) bf16
    const unsigned short* __restrict__ kB,   // (B,H,T,HD) bf16
    const float* __restrict__ em,            // (B,NL,T,T) f32 or null
    const unsigned char* __restrict__ pad,   // (B,T,T) or null
    unsigned short* __restrict__ P) {        // (B,H,T,T) bf16
    int id = blockIdx.x;
    // XCD swizzle: h-siblings (same b,it) share id%8 -> same XCD L2 for em reuse
    int c = id & 7, h = (id >> 3) & 7, g = id >> 6;
    int u = g * 8 + c;                 // 0..255
    int b = u >> 5, it = u & 31;
    int bh = b * Hn + h;
    int wave = threadIdx.x >> 6, lane = threadIdx.x & 63;
    int l16 = lane & 15, quad = lane >> 4;
    int i = it * 16 + l16;

    const int JC = Tn / 64;            // 8 j-chunks of 16 per wave

    // k fragments for this wave's 128 j rows: resident across the l loop
    const unsigned short* kp0 = kB + (size_t)bh * Tn * HDn + (size_t)l16 * HDn + quad * 8;
    short8 kf[JC][2];
#pragma unroll
    for (int jc = 0; jc < JC; ++jc) {
        const unsigned short* kp = kp0 + (size_t)(wave * JC + jc) * 16 * HDn;
        kf[jc][0] = *(const short8*)(kp);
        kf[jc][1] = *(const short8*)(kp + 32);
    }

    const unsigned short* ub = uR + (size_t)bh * NL * Tn * HDn + (size_t)i * HDn + quad * 8;
    const float* emB = EM ? (em + ((size_t)b * NL * Tn + i) * Tn) : nullptr;

    floatx4 sacc[JC] = {};
#pragma clang loop unroll(disable)
    for (int l = 0; l < NL; ++l) {
        short8 u0 = *(const short8*)(ub + (size_t)l * Tn * HDn);
        short8 u1 = *(const short8*)(ub + (size_t)l * Tn * HDn + 32);
#pragma unroll
        for (int jc = 0; jc < JC; ++jc) {
            int jt = wave * JC + jc;
            floatx4 gacc = {0, 0, 0, 0};
            gacc = __builtin_amdgcn_mfma_f32_16x16x32_bf16(kf[jc][0], u0, gacc, 0, 0, 0);
            gacc = __builtin_amdgcn_mfma_f32_16x16x32_bf16(kf[jc][1], u1, gacc, 0, 0, 0);
            if (EM) {
                floatx4 e4 = *(const floatx4*)(emB + (size_t)l * Tn * Tn + jt * 16 + quad * 4);
                sacc[jc] += e4 * gacc;
            } else {
                sacc[jc] = gacc;
            }
        }
    }

    // scale + pad mask + per-wave row max
    float mx = -3.0e38f;
    for (int jc = 0; jc < JC; ++jc) {
        int jt = wave * JC + jc;
        floatx4 v = sacc[jc] * SCALE;
        if (EM) {
            unsigned int pu = *(const unsigned int*)(pad + ((size_t)b * Tn + i) * Tn + jt * 16 + quad * 4);
            if (pu) {
                if (pu & 0x000000FFu) v[0] = -1.0e9f;
                if (pu & 0x0000FF00u) v[1] = -1.0e9f;
                if (pu & 0x00FF0000u) v[2] = -1.0e9f;
                if (pu & 0xFF000000u) v[3] = -1.0e9f;
            }
        }
        sacc[jc] = v;
        mx = fmaxf(mx, fmaxf(fmaxf(v[0], v[1]), fmaxf(v[2], v[3])));
    }
    mx = fmaxf(mx, __shfl_xor(mx, 16, 64));
    mx = fmaxf(mx, __shfl_xor(mx, 32, 64));

    __shared__ float redm[4][16];
    __shared__ float reds[4][16];
    if (quad == 0) redm[wave][l16] = mx;
    __syncthreads();
    mx = fmaxf(fmaxf(redm[0][l16], redm[1][l16]), fmaxf(redm[2][l16], redm[3][l16]));

    float sum = 0.0f;
    for (int jc = 0; jc < JC; ++jc) {
        floatx4 v = sacc[jc];
        v[0] = __expf(v[0] - mx); v[1] = __expf(v[1] - mx);
        v[2] = __expf(v[2] - mx); v[3] = __expf(v[3] - mx);
        sacc[jc] = v;
        sum += v[0] + v[1] + v[2] + v[3];
    }
    sum += __shfl_xor(sum, 16, 64);
    sum += __shfl_xor(sum, 32, 64);
    if (quad == 0) reds[wave][l16] = sum;
    __syncthreads();
    sum = (reds[0][l16] + reds[1][l16]) + (reds[2][l16] + reds[3][l16]);
    float inv = 1.0f / sum;

    unsigned short* prow = P + (size_t)bh * Tn * Tn + (size_t)i * Tn;
    for (int jc = 0; jc < JC; ++jc) {
        int jt = wave * JC + jc;
        floatx4 v = sacc[jc];
        ushort4 o;
        o.x = f2b(v[0] * inv); o.y = f2b(v[1] * inv);
        o.z = f2b(v[2] * inv); o.w = f2b(v[3] * inv);
        *(ushort4*)(prow + jt * 16 + quad * 4) = o;
    }
}

// ---------------------------------------------------------------------------
// LayerNorm over D=512: out = (a[row] + b2[row] - mean)/sqrt(var+eps)*s + bb
__global__ __launch_bounds__(256) void ln_kernel(
    const float* __restrict__ a, int a_trans, const float* __restrict__ b2,
    const float* __restrict__ s, const float* __restrict__ bb,
    float* __restrict__ outF, int out_trans, unsigned short* __restrict__ outB) {
    int row = blockIdx.x;            // b*Tn + t
    int b = row >> 9, t = row & (Tn - 1);
    int tid = threadIdx.x;
    size_t ia = a_trans ? ((size_t)(t * Bn + b)) * Dn : (size_t)row * Dn;
    size_t ir = (size_t)row * Dn;
    float x0 = a[ia + tid];
    float x1 = a[ia + tid + 256];
    if (b2) { x0 += b2[ir + tid]; x1 += b2[ir + tid + 256]; }
    float s1 = x0 + x1, s2 = x0 * x0 + x1 * x1;
    for (int off = 32; off; off >>= 1) {
        s1 += __shfl_xor(s1, off, 64);
        s2 += __shfl_xor(s2, off, 64);
    }
    __shared__ float red[2][4];
    int wave = tid >> 6, lane = tid & 63;
    if (lane == 0) { red[0][wave] = s1; red[1][wave] = s2; }
    __syncthreads();
    float ts1 = red[0][0] + red[0][1] + red[0][2] + red[0][3];
    float ts2 = red[1][0] + red[1][1] + red[1][2] + red[1][3];
    float mean = ts1 * (1.0f / Dn);
    float var = ts2 * (1.0f / Dn) - mean * mean;
    float rs = rsqrtf(var + 1e-5f);
    float y0 = (x0 - mean) * rs * s[tid] + bb[tid];
    float y1 = (x1 - mean) * rs * s[tid + 256] + bb[tid + 256];
    size_t io = out_trans ? ((size_t)(t * Bn + b)) * Dn : ir;
    if (outF) { outF[io + tid] = y0; outF[io + tid + 256] = y1; }
    if (outB) { outB[ir + tid] = f2b(y0); outB[ir + tid + 256] = f2b(y1); }
}

// ---------------------------------------------------------------------------
extern "C" void kernel_launch(void* const* d_in, const int* in_sizes, int n_in,
                              void* d_out, int out_size, void* d_ws, size_t ws_size,
                              hipStream_t stream) {
    const float* tgt      = (const float*)d_in[0];
    const float* em       = (const float*)d_in[1];
    const unsigned char* pad = (const unsigned char*)d_in[2];
    const float* memr     = (const float*)d_in[3];
    const float* sa_q_w   = (const float*)d_in[4];
    const float* sa_q_b   = (const float*)d_in[5];
    const float* sa_k_w   = (const float*)d_in[6];
    const float* sa_k_b   = (const float*)d_in[7];
    const float* sa_v_w   = (const float*)d_in[8];
    const float* sa_v_b   = (const float*)d_in[9];
    const float* sa_rel   = (const float*)d_in[10];
    const float* sa_out_w = (const float*)d_in[11];
    const float* sa_out_b = (const float*)d_in[12];
    const float* ca_in_w  = (const float*)d_in[13];
    const float* ca_in_b  = (const float*)d_in[14];
    const float* ca_out_w = (const float*)d_in[15];
    const float* ca_out_b = (const float*)d_in[16];
    const float* lin1_w   = (const float*)d_in[17];
    const float* lin1_b   = (const float*)d_in[18];
    const float* lin2_w   = (const float*)d_in[19];
    const float* lin2_b   = (const float*)d_in[20];
    const float* ln1_s    = (const float*)d_in[21];
    const float* ln1_b    = (const float*)d_in[22];
    const float* ln2_s    = (const float*)d_in[23];
    const float* ln2_b    = (const float*)d_in[24];
    const float* ln3_s    = (const float*)d_in[25];
    const float* ln3_b    = (const float*)d_in[26];

    const size_t BT = (size_t)Bn * Tn;   // 4096
    const size_t Q  = 1 << 18;           // 256K elems

    // ---- workspace carve-out ----
    char* ws = (char*)d_ws;
    size_t off = 0;
    auto alloc = [&](size_t bytes) -> char* {
        char* p = ws + off;
        off += (bytes + 255) & ~(size_t)255;
        return p;
    };
    unsigned short* xb   = (unsigned short*)alloc(BT * Dn * 2);
    unsigned short* mb   = (unsigned short*)alloc(BT * Dn * 2);
    unsigned short* wall = (unsigned short*)alloc((16 * Q + Ln * HDn * HDn) * 2);
    float*          bqkv = (float*)alloc(3 * Dn * 4);
    unsigned short* qb   = (unsigned short*)alloc(BT * Dn * 2);          // (B,H,T,HD)
    unsigned short* kb   = (unsigned short*)alloc(BT * Dn * 2);          // (B,H,T,HD)
    unsigned short* vtb  = (unsigned short*)alloc(BT * Dn * 2);          // (B,H,HD,T)
    unsigned short* ur   = (unsigned short*)alloc((size_t)Bn * Hn * Ln * Tn * HDn * 2);
    unsigned short* pb   = (unsigned short*)alloc((size_t)Bn * Hn * Tn * Tn * 2); // 32MB probs
    unsigned short* ob   = (unsigned short*)alloc(BT * Dn * 2);
    float*          t2f  = (float*)alloc(BT * Dn * 4);
    float*          x1f  = (float*)alloc(BT * Dn * 4);
    unsigned short* x1b  = (unsigned short*)alloc(BT * Dn * 2);
    float*          x2f  = (float*)alloc(BT * Dn * 4);
    unsigned short* x2b  = (unsigned short*)alloc(BT * Dn * 2);
    unsigned short* hid  = (unsigned short*)alloc(BT * Fn * 2);
    (void)ws_size; (void)in_sizes; (void)n_in; (void)out_size;

    // arena views
    unsigned short* wqkv = wall;
    unsigned short* wsao = wall + 3 * Q;
    unsigned short* wcain = wall + 4 * Q;
    unsigned short* wcao = wall + 7 * Q;
    unsigned short* wlin1 = wall + 8 * Q;
    unsigned short* wlin2 = wall + 12 * Q;
    unsigned short* wrel = wall + 16 * Q;

    auto gemm = [&](const unsigned short* A, const unsigned short* W, const float* bias,
                    void* C, void* C2, void* C3, int M, int N, int K, int lda, int ldw, int ldc,
                    long sA1, long sA2, long sW1, long sW2, long sC1, long sC2,
                    int zdiv, int batches, float alpha, int mode, int relu, int Tp) {
        dim3 g(N / 64, M / 64, batches);
        gemm_bf16<<<g, 256, 0, stream>>>(A, W, bias, C, C2, C3, M, N, K, lda, ldw, ldc,
                                         sA1, sA2, sW1, sW2, sC1, sC2, zdiv,
                                         alpha, mode, relu, Tp);
    };
    // 128x128 tile
    auto gemmBig = [&](const unsigned short* A, const unsigned short* W, const float* bias,
                       void* C, void* C2, void* C3, int M, int N, int K,
                       int lda, int ldw, int ldc, float alpha, int mode, int relu, int Tp) {
        dim3 g(N / 128, M / 128, 1);
        gemmT_bf16<4, 4><<<g, 256, 0, stream>>>(A, W, bias, C, C2, C3, K, lda, ldw, ldc,
                                                alpha, mode, relu, Tp);
    };
    // 128x64 tile (N=512 cases -> 256 blocks = 1/CU)
    auto gemmMed = [&](const unsigned short* A, const unsigned short* W, const float* bias,
                       void* C, void* C2, void* C3, int M, int N, int K,
                       int lda, int ldw, int ldc, float alpha, int mode, int relu, int Tp) {
        dim3 g(N / 64, M / 128, 1);
        gemmT_bf16<4, 2><<<g, 256, 0, stream>>>(A, W, bias, C, C2, C3, K, lda, ldw, ldc,
                                                alpha, mode, relu, Tp);
    };

    // ---- prep ----
    to_rows_bf16<<<dim3((BT * Dn + 255) / 256), 256, 0, stream>>>(tgt, xb, Tn);
    to_rows_bf16<<<dim3((BT * Dn + 255) / 256), 256, 0, stream>>>(memr, mb, Sn);
    conv_all<<<dim3((16 * Q + Ln * HDn * HDn + 3 * Dn + 255) / 256), 256, 0, stream>>>(
        sa_q_w, sa_k_w, sa_v_w, sa_out_w, ca_in_w, ca_out_w, lin1_w, lin2_w, sa_rel,
        sa_q_b, sa_k_b, sa_v_b, wall, bqkv);

    // ---- self-attention ----
    // fused q,k,v: (B,H,T,HD) x2 + v as (B,H,HD,T)
    gemmBig(xb, wqkv, bqkv, qb, kb, vtb, (int)BT, 3 * Dn, Dn, Dn, Dn, 0, 1.0f, 4, 0, Tn);
    // uR[b,h,l] = q[b,h] @ R_l^T  (batched over B*H*L)
    gemm(qb, wrel, nullptr, ur, nullptr, nullptr, Tn, HDn, HDn, HDn, HDn, HDn,
         (long)Tn * HDn, 0, 0, (long)HDn * HDn, (long)Ln * Tn * HDn, (long)Tn * HDn,
         Ln, Bn * Hn * Ln, 1.0f, 1, 0, 0);
    // fused rel-scores + em + scale + pad + softmax -> bf16 P
    relsoft<Ln, true><<<dim3(2048), 256, 0, stream>>>(ur, kb, em, pad, pb);
    // O = P @ V
    gemm(pb, vtb, nullptr, ob, nullptr, nullptr, Tn, HDn, Tn, Tn, Tn, Dn,
         (long)Hn * Tn * Tn, (long)Tn * Tn, (long)Hn * HDn * Tn, (long)HDn * Tn,
         (long)Tn * Dn, 64, Hn, Bn * Hn, 1.0f, 1, 0, 0);
    gemmMed(ob, wsao, sa_out_b, t2f, nullptr, nullptr, (int)BT, Dn, Dn, Dn, Dn, Dn,
            1.0f, 0, 0, 0);
    ln_kernel<<<dim3((int)BT), 256, 0, stream>>>(tgt, 1, t2f, ln1_s, ln1_b, x1f, 0, x1b);

    // ---- cross-attention ----
    gemmMed(x1b, wcain, ca_in_b, qb, nullptr, nullptr, (int)BT, Dn, Dn, Dn, Dn, 0,
            1.0f, 2, 0, Tn);
    // fused k,v from memory
    gemmBig(mb, wcain + (size_t)Dn * Dn, ca_in_b + Dn, kb, vtb, nullptr, (int)BT, 2 * Dn, Dn,
            Dn, Dn, 0, 1.0f, 5, 0, Sn);
    // fused qk^T + scale + softmax -> bf16 P
    relsoft<1, false><<<dim3(2048), 256, 0, stream>>>(qb, kb, nullptr, nullptr, pb);
    gemm(pb, vtb, nullptr, ob, nullptr, nullptr, Tn, HDn, Sn, Sn, Sn, Dn,
         (long)Hn * Tn * Sn, (long)Tn * Sn, (long)Hn * HDn * Sn, (long)HDn * Sn,
         (long)Tn * Dn, 64, Hn, Bn * Hn, 1.0f, 1, 0, 0);
    gemmMed(ob, wcao, ca_out_b, t2f, nullptr, nullptr, (int)BT, Dn, Dn, Dn, Dn, Dn,
            1.0f, 0, 0, 0);
    ln_kernel<<<dim3((int)BT), 256, 0, stream>>>(x1f, 0, t2f, ln2_s, ln2_b, x2f, 0, x2b);

    // ---- FFN ----
    gemmBig(x2b, wlin1, lin1_b, hid, nullptr, nullptr, (int)BT, Fn, Dn, Dn, Dn, Fn,
            1.0f, 1, 1, 0);
    gemmMed(hid, wlin2, lin2_b, t2f, nullptr, nullptr, (int)BT, Dn, Fn, Fn, Fn, Dn,
            1.0f, 0, 0, 0);
    ln_kernel<<<dim3((int)BT), 256, 0, stream>>>(x2f, 0, t2f, ln3_s, ln3_b, (float*)d_out, 1, nullptr);
}